// Round 14
// baseline (540.366 us; speedup 1.0000x reference)
//
#include <hip/hip_runtime.h>
#include <hip/hip_bf16.h>
#include <math.h>

// Problem constants
constexpr int B    = 16;
constexpr int H    = 96;
constexpr int W    = 96;
constexpr int C    = 512;
constexpr int D    = 64;
constexpr int NBH  = 24;          // blocks per side
constexpr int NB   = 576;         // num_block_tot
constexpr int HW   = 9216;
constexpr int TOPK = 16;
constexpr int TK2  = 32;          // 2*TOPK
constexpr int NCAND = 40;         // selection threshold rank (exact fp32 re-rank after)
constexpr int CAP  = 64;          // candidate cap (ties)

typedef __attribute__((ext_vector_type(8))) short bf16x8;
typedef __attribute__((ext_vector_type(4))) float f32x4;

__device__ inline unsigned short f2bf(float x) {   // fp32 -> bf16 RNE
    unsigned int u = __float_as_uint(x);
    return (unsigned short)((u + 0x7FFFu + ((u >> 16) & 1u)) >> 16);
}

// ---------------------------------------------------------------- K0: transpose weights
__global__ void k_transpose(const float* __restrict__ Wk, const float* __restrict__ Wq,
                            float* __restrict__ WkT, float* __restrict__ WqT) {
    int idx = blockIdx.x * 256 + threadIdx.x;   // over C*D
    if (idx < C * D) {
        int c = idx >> 6, d = idx & 63;
        WkT[c * D + d] = Wk[d * C + c];
        WqT[c * D + d] = Wq[d * C + c];
    }
}

// ---------------------------------------------------------------- K1: pool + k (fp32, frozen numerics)
// v7: x via wave-uniform scalar path (readfirstlane base -> s_load candidates);
// w via incremental pointers + imm offsets; a/e panels interleaved for ILP.
// NUMERICS FROZEN: per-(px,d) asc-c fmaf chain split at c=384; k=(a+e)+bk;
// mean sequential (dy,dx) then *0.0625f.
__global__ __launch_bounds__(256, 4) void k_embed(
    const float* __restrict__ src,
    const float* __restrict__ WkT, const float* __restrict__ bk,
    float* __restrict__ k32, float* __restrict__ emb) {
    __shared__ float sS[16][C];    // 32 KB, mean only

    int t   = threadIdx.x;
    int blk = blockIdx.x;
    int b = blk / NB, n = blk % NB;
    int nh = n / NBH, nw = n % NBH;
    int y0 = nh * 4, x0 = nw * 4;

    // stage 16 px rows (coalesced float4) for the mean
    #pragma unroll
    for (int r = 0; r < 8; ++r) {
        int f4 = r * 256 + t;
        int px = f4 >> 7, c4 = f4 & 127;
        int dy = px >> 2, dx = px & 3;
        ((float4*)sS[px])[c4] =
            *(const float4*)&src[((size_t)(b * H + y0 + dy) * W + (x0 + dx)) * C + c4 * 4];
    }
    __syncthreads();

    // block mean -> emb (frozen sequential (dy,dx) order)
    #pragma unroll
    for (int s = 0; s < 2; ++s) {
        int cc = s * 256 + t;
        float sum = sS[0][cc];
        #pragma unroll
        for (int px = 1; px < 16; ++px) sum += sS[px][cc];
        emb[((size_t)b * NB + n) * C + cc] = sum * 0.0625f;
    }

    // k chains: wave pg -> px {4pg..4pg+3} (= row dy=pg, dx=0..3), lane d
    int d  = t & 63;
    int pg = __builtin_amdgcn_readfirstlane(t >> 6);   // wave-uniform

    const float* xb  = src + ((size_t)(b * H + y0 + pg) * W + x0) * C;  // uniform base
    const float* wpa = WkT + d;              // panel a walker (cc = 0..383)
    const float* wpe = WkT + 384 * D + d;    // panel e walker (cc = 384..511)

    float a0 = 0.f, a1 = 0.f, a2 = 0.f, a3 = 0.f;
    float e0 = 0.f, e1 = 0.f, e2 = 0.f, e3 = 0.f;

    // interleaved: a-quad cg and e-quad 96+cg, cg = 0..31 (8 independent chains)
    #pragma unroll 2
    for (int cg = 0; cg < 32; ++cg) {
        float4 xa0 = *(const float4*)&xb[cg * 4];
        float4 xa1 = *(const float4*)&xb[512 + cg * 4];
        float4 xa2 = *(const float4*)&xb[1024 + cg * 4];
        float4 xa3 = *(const float4*)&xb[1536 + cg * 4];
        float4 xe0 = *(const float4*)&xb[384 + cg * 4];
        float4 xe1 = *(const float4*)&xb[896 + cg * 4];
        float4 xe2 = *(const float4*)&xb[1408 + cg * 4];
        float4 xe3 = *(const float4*)&xb[1920 + cg * 4];
        float wa[4], we[4];
        #pragma unroll
        for (int j = 0; j < 4; ++j) { wa[j] = wpa[j * D]; we[j] = wpe[j * D]; }
        wpa += 4 * D; wpe += 4 * D;
        const float* fa0 = (const float*)&xa0;
        const float* fa1 = (const float*)&xa1;
        const float* fa2 = (const float*)&xa2;
        const float* fa3 = (const float*)&xa3;
        const float* fe0 = (const float*)&xe0;
        const float* fe1 = (const float*)&xe1;
        const float* fe2 = (const float*)&xe2;
        const float* fe3 = (const float*)&xe3;
        #pragma unroll
        for (int j = 0; j < 4; ++j) {      // ascending c within each chain
            a0 = __builtin_fmaf(fa0[j], wa[j], a0);
            a1 = __builtin_fmaf(fa1[j], wa[j], a1);
            a2 = __builtin_fmaf(fa2[j], wa[j], a2);
            a3 = __builtin_fmaf(fa3[j], wa[j], a3);
            e0 = __builtin_fmaf(fe0[j], we[j], e0);
            e1 = __builtin_fmaf(fe1[j], we[j], e1);
            e2 = __builtin_fmaf(fe2[j], we[j], e2);
            e3 = __builtin_fmaf(fe3[j], we[j], e3);
        }
    }
    // tail: a-quads cg = 32..95
    #pragma unroll 2
    for (int cg = 32; cg < 96; ++cg) {
        float4 xa0 = *(const float4*)&xb[cg * 4];
        float4 xa1 = *(const float4*)&xb[512 + cg * 4];
        float4 xa2 = *(const float4*)&xb[1024 + cg * 4];
        float4 xa3 = *(const float4*)&xb[1536 + cg * 4];
        float wa[4];
        #pragma unroll
        for (int j = 0; j < 4; ++j) wa[j] = wpa[j * D];
        wpa += 4 * D;
        const float* fa0 = (const float*)&xa0;
        const float* fa1 = (const float*)&xa1;
        const float* fa2 = (const float*)&xa2;
        const float* fa3 = (const float*)&xa3;
        #pragma unroll
        for (int j = 0; j < 4; ++j) {
            a0 = __builtin_fmaf(fa0[j], wa[j], a0);
            a1 = __builtin_fmaf(fa1[j], wa[j], a1);
            a2 = __builtin_fmaf(fa2[j], wa[j], a2);
            a3 = __builtin_fmaf(fa3[j], wa[j], a3);
        }
    }

    float bkd = bk[d];
    #pragma unroll
    for (int u = 0; u < 4; ++u) {
        size_t p = (size_t)(y0 + pg) * W + (x0 + u);
        float a = (u == 0 ? a0 : u == 1 ? a1 : u == 2 ? a2 : a3);
        float e = (u == 0 ? e0 : u == 1 ? e1 : u == 2 ? e2 : e3);
        k32[((size_t)b * HW + p) * D + d] = (a + e) + bkd;
    }
}

// ---------------------------------------------------------------- K1b: q from emb (frozen chain, R11)
__global__ __launch_bounds__(256) void k_q(
    const float* __restrict__ emb, const float* __restrict__ WqT,
    const float* __restrict__ bq, float* __restrict__ q32) {
    int t  = threadIdx.x;
    int d  = t & 63;
    int ng = t >> 6;
    int r0 = blockIdx.x * 16 + ng * 4;
    const float* e0 = emb + (size_t)(r0 + 0) * C;
    const float* e1 = emb + (size_t)(r0 + 1) * C;
    const float* e2 = emb + (size_t)(r0 + 2) * C;
    const float* e3 = emb + (size_t)(r0 + 3) * C;

    float qa0 = 0.f, qa1 = 0.f, qa2 = 0.f, qa3 = 0.f;
    float qe0 = 0.f, qe1 = 0.f, qe2 = 0.f, qe3 = 0.f;
    #pragma unroll 2
    for (int cg = 0; cg < 96; ++cg) {
        float4 v0 = *(const float4*)&e0[cg * 4];
        float4 v1 = *(const float4*)&e1[cg * 4];
        float4 v2 = *(const float4*)&e2[cg * 4];
        float4 v3 = *(const float4*)&e3[cg * 4];
        float w0 = WqT[(cg * 4 + 0) * D + d];
        float w1 = WqT[(cg * 4 + 1) * D + d];
        float w2 = WqT[(cg * 4 + 2) * D + d];
        float w3 = WqT[(cg * 4 + 3) * D + d];
        const float* f0 = (const float*)&v0;
        const float* f1 = (const float*)&v1;
        const float* f2 = (const float*)&v2;
        const float* f3 = (const float*)&v3;
        float wj[4] = {w0, w1, w2, w3};
        #pragma unroll
        for (int j = 0; j < 4; ++j) {
            qa0 = __builtin_fmaf(f0[j], wj[j], qa0);
            qa1 = __builtin_fmaf(f1[j], wj[j], qa1);
            qa2 = __builtin_fmaf(f2[j], wj[j], qa2);
            qa3 = __builtin_fmaf(f3[j], wj[j], qa3);
        }
    }
    #pragma unroll 2
    for (int cg = 96; cg < 128; ++cg) {
        float4 v0 = *(const float4*)&e0[cg * 4];
        float4 v1 = *(const float4*)&e1[cg * 4];
        float4 v2 = *(const float4*)&e2[cg * 4];
        float4 v3 = *(const float4*)&e3[cg * 4];
        float w0 = WqT[(cg * 4 + 0) * D + d];
        float w1 = WqT[(cg * 4 + 1) * D + d];
        float w2 = WqT[(cg * 4 + 2) * D + d];
        float w3 = WqT[(cg * 4 + 3) * D + d];
        const float* f0 = (const float*)&v0;
        const float* f1 = (const float*)&v1;
        const float* f2 = (const float*)&v2;
        const float* f3 = (const float*)&v3;
        float wj[4] = {w0, w1, w2, w3};
        #pragma unroll
        for (int j = 0; j < 4; ++j) {
            qe0 = __builtin_fmaf(f0[j], wj[j], qe0);
            qe1 = __builtin_fmaf(f1[j], wj[j], qe1);
            qe2 = __builtin_fmaf(f2[j], wj[j], qe2);
            qe3 = __builtin_fmaf(f3[j], wj[j], qe3);
        }
    }
    float bqd = bq[d];
    q32[(size_t)(r0 + 0) * D + d] = (qa0 + qe0) + bqd;
    q32[(size_t)(r0 + 1) * D + d] = (qa1 + qe1) + bqd;
    q32[(size_t)(r0 + 2) * D + d] = (qa2 + qe2) + bqd;
    q32[(size_t)(r0 + 3) * D + d] = (qa3 + qe3) + bqd;
}

// ---------------------------------------------------------------- K2: scores SHADOW via bf16 MFMA (R13)
__global__ __launch_bounds__(256, 4) void k_scores(
    const float* __restrict__ q32, const float* __restrict__ k32,
    _Float16* __restrict__ S16) {
    __shared__ unsigned short sQ[64 * 72];       // [row n][d], pad 72
    __shared__ unsigned short sK[64 * 72];       // [row p][d]
    __shared__ unsigned short sOut[4][16 * 72];  // per-wave repack

    int t  = threadIdx.x;
    int p0 = blockIdx.x * 64;      // 144
    int n0 = blockIdx.y * 64;      // 9
    int b  = blockIdx.z;

    const float* qb = q32 + ((size_t)b * NB + n0) * D;
    const float* kb = k32 + ((size_t)b * HW + p0) * D;

    #pragma unroll
    for (int r = 0; r < 4; ++r) {
        int L = r * 256 + t;
        int row = L >> 4, c4 = L & 15;
        float4 vq = *(const float4*)&qb[(size_t)row * D + c4 * 4];
        float4 vk = *(const float4*)&kb[(size_t)row * D + c4 * 4];
        ushort4 hq, hk;
        hq.x = f2bf(vq.x); hq.y = f2bf(vq.y); hq.z = f2bf(vq.z); hq.w = f2bf(vq.w);
        hk.x = f2bf(vk.x); hk.y = f2bf(vk.y); hk.z = f2bf(vk.z); hk.w = f2bf(vk.w);
        *(ushort4*)&sQ[row * 72 + c4 * 4] = hq;
        *(ushort4*)&sK[row * 72 + c4 * 4] = hk;
    }
    __syncthreads();

    int w = t >> 6, l = t & 63;
    int fr = l & 15;
    int kb8 = (l >> 4) * 8;

    f32x4 acc[4] = {f32x4{0,0,0,0}, f32x4{0,0,0,0}, f32x4{0,0,0,0}, f32x4{0,0,0,0}};
    #pragma unroll
    for (int ks = 0; ks < 2; ++ks) {
        bf16x8 a = *(const bf16x8*)&sQ[(16 * w + fr) * 72 + ks * 32 + kb8];
        #pragma unroll
        for (int f = 0; f < 4; ++f) {
            bf16x8 bb = *(const bf16x8*)&sK[(16 * f + fr) * 72 + ks * 32 + kb8];
            acc[f] = __builtin_amdgcn_mfma_f32_16x16x32_bf16(a, bb, acc[f], 0, 0, 0);
        }
    }

    unsigned short* so = &sOut[w][0];
    #pragma unroll
    for (int f = 0; f < 4; ++f)
        #pragma unroll
        for (int r = 0; r < 4; ++r) {
            _Float16 h = (_Float16)acc[f][r];
            so[((l >> 4) * 4 + r) * 72 + 16 * f + (l & 15)] = *(unsigned short*)&h;
        }
    __syncthreads();

    _Float16* Sb = S16 + (size_t)b * NB * HW;
    int orow = l >> 2, oc = (l & 3) * 16;
    uint4 v0 = *(const uint4*)&sOut[w][orow * 72 + oc];
    uint4 v1 = *(const uint4*)&sOut[w][orow * 72 + oc + 8];
    size_t base = (size_t)(n0 + 16 * w + orow) * HW + (p0 + oc);
    *(uint4*)&Sb[base]     = v0;
    *(uint4*)&Sb[base + 8] = v1;
}

// ---------------------------------------------------------------- K3: per-row top-k via 2-pass radix select
__global__ __launch_bounds__(256) void k_topk(
    const _Float16* __restrict__ S16,
    const float* __restrict__ q32, const float* __restrict__ k32,
    int* __restrict__ cidx, float* __restrict__ cval, double* __restrict__ rowss) {
    __shared__ int    hist[4][256];
    __shared__ int    sfx[256];
    __shared__ int    b0s, mAbove, thrS, gcnt;
    __shared__ int    cps[CAP];
    __shared__ float  cv[CAP];
    __shared__ int    cp[CAP];
    __shared__ float  sv[CAP];
    __shared__ int    sp[CAP];
    __shared__ double ssq[TOPK];

    int t   = threadIdx.x;
    int row = blockIdx.x;
    int b = row / NB, n = row % NB;
    int wid = t >> 6;

    #pragma unroll
    for (int w = 0; w < 4; ++w) hist[w][t] = 0;
    if (t == 0) gcnt = 0;
    __syncthreads();

    const unsigned short* Srow = (const unsigned short*)(S16 + (size_t)row * HW);
    unsigned int my[36];
    #pragma unroll
    for (int c = 0; c < 9; ++c) {
        ushort4 v4 = ((const ushort4*)Srow)[c * 256 + t];
        #pragma unroll
        for (int j = 0; j < 4; ++j) {
            unsigned int h = (j == 0 ? v4.x : j == 1 ? v4.y : j == 2 ? v4.z : v4.w);
            unsigned int m = (h & 0x8000u) ? (h ^ 0xFFFFu) : (h | 0x8000u);
            int p = (c * 256 + t) * 4 + j;
            int hh = p / W, ww = p - hh * W;
            if (((hh >> 2) * NBH + (ww >> 2)) == n) m = 0;
            my[c * 4 + j] = m;
            atomicAdd(&hist[wid][m >> 8], 1);
        }
    }
    __syncthreads();

    sfx[t] = hist[0][t] + hist[1][t] + hist[2][t] + hist[3][t];
    __syncthreads();
    #pragma unroll
    for (int off = 1; off < 256; off <<= 1) {
        int v = (t + off < 256) ? sfx[t + off] : 0;
        __syncthreads();
        sfx[t] += v;
        __syncthreads();
    }
    if (sfx[t] >= NCAND && (t == 255 || sfx[t + 1] < NCAND)) {
        b0s = t; mAbove = (t == 255) ? 0 : sfx[t + 1];
    }
    __syncthreads();
    int b0 = b0s, mab = mAbove;
    __syncthreads();

    #pragma unroll
    for (int w = 0; w < 4; ++w) hist[w][t] = 0;
    __syncthreads();
    #pragma unroll
    for (int i = 0; i < 36; ++i)
        if ((int)(my[i] >> 8) == b0) atomicAdd(&hist[wid][my[i] & 255u], 1);
    __syncthreads();
    sfx[t] = hist[0][t] + hist[1][t] + hist[2][t] + hist[3][t];
    __syncthreads();
    #pragma unroll
    for (int off = 1; off < 256; off <<= 1) {
        int v = (t + off < 256) ? sfx[t + off] : 0;
        __syncthreads();
        sfx[t] += v;
        __syncthreads();
    }
    if (mab + sfx[t] >= NCAND && (t == 255 || mab + sfx[t + 1] < NCAND))
        thrS = (b0 << 8) | t;
    __syncthreads();
    unsigned int thr = (unsigned int)thrS;

    #pragma unroll
    for (int i = 0; i < 36; ++i) {
        if (my[i] >= thr) {
            int pos = atomicAdd(&gcnt, 1);
            if (pos < CAP) {
                int c = i >> 2, j = i & 3;
                cps[pos] = (c * 256 + t) * 4 + j;
            }
        }
    }
    __syncthreads();
    int M = min(gcnt, CAP);

    // exact fp32 re-rank — np.einsum SSE order, no FMA (NUMERICS FROZEN)
    if (t < M) {
        #pragma clang fp contract(off)
        int p = cps[t];
        const float* qr = q32 + (size_t)row * D;
        const float* kr = k32 + ((size_t)b * HW + p) * D;
        float L0 = 0.f, L1 = 0.f, L2 = 0.f, L3 = 0.f;
        #pragma unroll
        for (int j = 0; j < 16; ++j) {
            L0 = L0 + qr[4 * j + 0] * kr[4 * j + 0];
            L1 = L1 + qr[4 * j + 1] * kr[4 * j + 1];
            L2 = L2 + qr[4 * j + 2] * kr[4 * j + 2];
            L3 = L3 + qr[4 * j + 3] * kr[4 * j + 3];
        }
        cv[t] = (L0 + L1) + (L2 + L3);
        cp[t] = p;
    }
    __syncthreads();

    if (t < M) {
        float v = cv[t]; int p = cp[t];
        int rank = 0;
        for (int j = 0; j < M; ++j) {
            float vj = cv[j];
            rank += (vj > v) || (vj == v && cp[j] < p);
        }
        sv[rank] = v; sp[rank] = p;
    }
    __syncthreads();

    if (t < TK2) {
        cval[(size_t)row * TK2 + t] = sv[t];
        cidx[(size_t)row * TK2 + t] = sp[t];
    }
    if (t < TOPK) {
        double vi = (double)sv[t], s = 0.0;
        #pragma unroll
        for (int j = 0; j < TK2; ++j) { double dd = vi - (double)sv[j]; s += dd * dd; }
        ssq[t] = s;
    }
    __syncthreads();
    if (t == 0) {
        double s = 0.0;
        #pragma unroll
        for (int i = 0; i < TOPK; ++i) s += ssq[i];
        rowss[row] = s;
    }
}

// ---------------------------------------------------------------- K4: per-batch RMS -> scale
__global__ void k_rms(const double* __restrict__ rowss, double* __restrict__ scale) {
    __shared__ double sb[256];
    int b = blockIdx.x, t = threadIdx.x;
    double s = 0.0;
    for (int r = t; r < NB; r += 256) s += rowss[b * NB + r];
    sb[t] = s; __syncthreads();
    for (int st = 128; st > 0; st >>= 1) {
        if (t < st) sb[t] += sb[t + st];
        __syncthreads();
    }
    if (t == 0) {
        double rms = sqrt(sb[0] / ((double)NB * TOPK * TK2));
        scale[b] = 10.0 / (rms + 1e-3);
    }
}

// ---------------------------------------------------------------- K5: finalize — SOLE writer of d_out (float32)
__global__ __launch_bounds__(256) void k_final(
    const int* __restrict__ cidx, const float* __restrict__ cval,
    const double* __restrict__ scale, float* __restrict__ out) {
    __shared__ double sv[16][TK2];
    int t = threadIdx.x;
    int row0 = blockIdx.x * 16;
    for (int idx = t; idx < 16 * TK2; idx += 256) {
        int r = idx >> 5, j = idx & 31;
        sv[r][j] = (double)cval[(size_t)(row0 + r) * TK2 + j];
    }
    __syncthreads();
    int r = t >> 4, i = t & 15;
    int row = row0 + r;
    double scb = scale[row / NB];
    double vi = sv[r][i];
    double s = 0.0;
    #pragma unroll
    for (int j = 0; j < TK2; ++j) {
        double x = (vi - sv[r][j]) * scb;
        s += 1.0 / (1.0 + exp(-x));
    }
    out[(size_t)B * NB * TOPK + (size_t)row * TOPK + i] = (float)tanh(s - (double)TOPK);
    out[(size_t)row * TOPK + i] = (float)cidx[(size_t)row * TK2 + i];
}

// ---------------------------------------------------------------- sentinel fill (ws too small)
__global__ void k_fill(float* out, int nelem) {
    int i = blockIdx.x * 256 + threadIdx.x;
    if (i < nelem) out[i] = -12345.0f;
}

// ---------------------------------------------------------------- launch
extern "C" void kernel_launch(void* const* d_in, const int* in_sizes, int n_in,
                              void* d_out, int out_size, void* d_ws, size_t ws_size,
                              hipStream_t stream) {
    const float* src = (const float*)d_in[0];
    const float* Wq  = (const float*)d_in[1];
    const float* bq  = (const float*)d_in[2];
    const float* Wk  = (const float*)d_in[3];
    const float* bk  = (const float*)d_in[4];
    float* out = (float*)d_out;

    char* ws = (char*)d_ws;
    size_t oWkT = 0;
    size_t oWqT = oWkT + (size_t)C * D * 4;
    size_t oQ   = oWqT + (size_t)C * D * 4;
    size_t oK   = oQ   + (size_t)B * NB * D * 4;
    size_t oS   = oK   + (size_t)B * HW * D * 4;
    size_t oEmb = oS   + (size_t)B * NB * HW * 2;
    size_t oCV  = oEmb + (size_t)B * NB * C * 4;
    size_t oCI  = oCV  + (size_t)B * NB * TK2 * 4;
    size_t oRS  = oCI  + (size_t)B * NB * TK2 * 4;
    size_t oSc  = oRS  + (size_t)B * NB * 8;
    size_t need = oSc  + (size_t)B * 8;

    if (ws_size < need) {
        k_fill<<<(out_size + 255) / 256, 256, 0, stream>>>(out, out_size);
        return;
    }

    float*     WkT  = (float*)(ws + oWkT);
    float*     WqT  = (float*)(ws + oWqT);
    float*     q32  = (float*)(ws + oQ);
    float*     k32  = (float*)(ws + oK);
    _Float16*  S16  = (_Float16*)(ws + oS);
    float*     emb  = (float*)(ws + oEmb);
    float*     cval = (float*)(ws + oCV);
    int*       cidx = (int*)(ws + oCI);
    double*    rss  = (double*)(ws + oRS);
    double*    scl  = (double*)(ws + oSc);

    k_transpose<<<(C * D + 255) / 256, 256, 0, stream>>>(Wk, Wq, WkT, WqT);
    k_embed<<<B * NB, 256, 0, stream>>>(src, WkT, bk, k32, emb);
    k_q<<<B * NB / 16, 256, 0, stream>>>(emb, WqT, bq, q32);
    k_scores<<<dim3(HW / 64, NB / 64, B), 256, 0, stream>>>(q32, k32, S16);
    k_topk<<<B * NB, 256, 0, stream>>>(S16, q32, k32, cidx, cval, rss);
    k_rms<<<B, 256, 0, stream>>>(rss, scl);
    k_final<<<B * NB / 16, 256, 0, stream>>>(cidx, cval, scl, out);
}

// Round 15
// 488.184 us; speedup vs baseline: 1.1069x; 1.1069x over previous
//
#include <hip/hip_runtime.h>
#include <hip/hip_bf16.h>
#include <math.h>

// Problem constants
constexpr int B    = 16;
constexpr int H    = 96;
constexpr int W    = 96;
constexpr int C    = 512;
constexpr int D    = 64;
constexpr int NBH  = 24;          // blocks per side
constexpr int NB   = 576;         // num_block_tot
constexpr int HW   = 9216;
constexpr int TOPK = 16;
constexpr int TK2  = 32;          // 2*TOPK
constexpr int NCAND = 40;         // selection threshold rank (exact fp32 re-rank after)
constexpr int CAP  = 64;          // candidate cap (ties)

typedef __attribute__((ext_vector_type(8))) short bf16x8;
typedef __attribute__((ext_vector_type(4))) float f32x4;

__device__ inline unsigned short f2bf(float x) {   // fp32 -> bf16 RNE
    unsigned int u = __float_as_uint(x);
    return (unsigned short)((u + 0x7FFFu + ((u >> 16) & 1u)) >> 16);
}

// ---------------------------------------------------------------- K0: transpose weights
__global__ void k_transpose(const float* __restrict__ Wk, const float* __restrict__ Wq,
                            float* __restrict__ WkT, float* __restrict__ WqT) {
    int idx = blockIdx.x * 256 + threadIdx.x;   // over C*D
    if (idx < C * D) {
        int c = idx >> 6, d = idx & 63;
        WkT[c * D + d] = Wk[d * C + c];
        WqT[c * D + d] = Wq[d * C + c];
    }
}

// ---------------------------------------------------------------- K1: pool + k (fp32, frozen numerics)
// v8: R11 inner loop verbatim, but LDS halved (16 KB) via two-pass c-staging ->
// 8 blocks/CU occupancy. Chain order preserved: a gets cc 0..255 then 256..383
// ascending; e gets 384..511. Mean per-c within its half, sequential (dy,dx).
__global__ __launch_bounds__(256, 8) void k_embed(
    const float* __restrict__ src,
    const float* __restrict__ WkT, const float* __restrict__ bk,
    float* __restrict__ k32, float* __restrict__ emb) {
    __shared__ float sS[16][256];   // 16 KB half-c stage

    int t   = threadIdx.x;
    int blk = blockIdx.x;
    int b = blk / NB, n = blk % NB;
    int nh = n / NBH, nw = n % NBH;
    int y0 = nh * 4, x0 = nw * 4;

    int d = t & 63, pg = t >> 6;

    float a0 = 0.f, a1 = 0.f, a2 = 0.f, a3 = 0.f;   // panel a (c < 384)
    float e0 = 0.f, e1 = 0.f, e2 = 0.f, e3 = 0.f;   // panel e (c >= 384)

    // ================= half 0: c in [0, 256) =================
    #pragma unroll
    for (int r = 0; r < 4; ++r) {
        int f4 = r * 256 + t;
        int px = f4 >> 6, c4 = f4 & 63;
        int dy = px >> 2, dx = px & 3;
        ((float4*)sS[px])[c4] =
            *(const float4*)&src[((size_t)(b * H + y0 + dy) * W + (x0 + dx)) * C + c4 * 4];
    }
    __syncthreads();

    {   // mean for c = t (frozen sequential (dy,dx) order)
        float sum = sS[0][t];
        #pragma unroll
        for (int px = 1; px < 16; ++px) sum += sS[px][t];
        emb[((size_t)b * NB + n) * C + t] = sum * 0.0625f;
    }

    {
        const float* s0 = sS[pg * 4 + 0];
        const float* s1 = sS[pg * 4 + 1];
        const float* s2 = sS[pg * 4 + 2];
        const float* s3 = sS[pg * 4 + 3];
        #pragma unroll 2
        for (int cg = 0; cg < 64; ++cg) {           // cc = cg*4+j in [0,256) -> a
            float4 x0v = *(const float4*)&s0[cg * 4];
            float4 x1v = *(const float4*)&s1[cg * 4];
            float4 x2v = *(const float4*)&s2[cg * 4];
            float4 x3v = *(const float4*)&s3[cg * 4];
            float w0 = WkT[(cg * 4 + 0) * D + d];
            float w1 = WkT[(cg * 4 + 1) * D + d];
            float w2 = WkT[(cg * 4 + 2) * D + d];
            float w3 = WkT[(cg * 4 + 3) * D + d];
            const float* x0f = (const float*)&x0v;
            const float* x1f = (const float*)&x1v;
            const float* x2f = (const float*)&x2v;
            const float* x3f = (const float*)&x3v;
            float wj[4] = {w0, w1, w2, w3};
            #pragma unroll
            for (int j = 0; j < 4; ++j) {
                a0 = __builtin_fmaf(x0f[j], wj[j], a0);
                a1 = __builtin_fmaf(x1f[j], wj[j], a1);
                a2 = __builtin_fmaf(x2f[j], wj[j], a2);
                a3 = __builtin_fmaf(x3f[j], wj[j], a3);
            }
        }
    }
    __syncthreads();   // all readers of half-0 done

    // ================= half 1: c in [256, 512) =================
    #pragma unroll
    for (int r = 0; r < 4; ++r) {
        int f4 = r * 256 + t;
        int px = f4 >> 6, c4 = f4 & 63;
        int dy = px >> 2, dx = px & 3;
        ((float4*)sS[px])[c4] =
            *(const float4*)&src[((size_t)(b * H + y0 + dy) * W + (x0 + dx)) * C + 256 + c4 * 4];
    }
    __syncthreads();

    {   // mean for c = 256 + t
        float sum = sS[0][t];
        #pragma unroll
        for (int px = 1; px < 16; ++px) sum += sS[px][t];
        emb[((size_t)b * NB + n) * C + 256 + t] = sum * 0.0625f;
    }

    {
        const float* s0 = sS[pg * 4 + 0];
        const float* s1 = sS[pg * 4 + 1];
        const float* s2 = sS[pg * 4 + 2];
        const float* s3 = sS[pg * 4 + 3];
        #pragma unroll 2
        for (int cg = 0; cg < 32; ++cg) {           // cc in [256,384) -> a (ascending)
            float4 x0v = *(const float4*)&s0[cg * 4];
            float4 x1v = *(const float4*)&s1[cg * 4];
            float4 x2v = *(const float4*)&s2[cg * 4];
            float4 x3v = *(const float4*)&s3[cg * 4];
            float w0 = WkT[(256 + cg * 4 + 0) * D + d];
            float w1 = WkT[(256 + cg * 4 + 1) * D + d];
            float w2 = WkT[(256 + cg * 4 + 2) * D + d];
            float w3 = WkT[(256 + cg * 4 + 3) * D + d];
            const float* x0f = (const float*)&x0v;
            const float* x1f = (const float*)&x1v;
            const float* x2f = (const float*)&x2v;
            const float* x3f = (const float*)&x3v;
            float wj[4] = {w0, w1, w2, w3};
            #pragma unroll
            for (int j = 0; j < 4; ++j) {
                a0 = __builtin_fmaf(x0f[j], wj[j], a0);
                a1 = __builtin_fmaf(x1f[j], wj[j], a1);
                a2 = __builtin_fmaf(x2f[j], wj[j], a2);
                a3 = __builtin_fmaf(x3f[j], wj[j], a3);
            }
        }
        #pragma unroll 2
        for (int cg = 32; cg < 64; ++cg) {          // cc in [384,512) -> e (ascending)
            float4 x0v = *(const float4*)&s0[cg * 4];
            float4 x1v = *(const float4*)&s1[cg * 4];
            float4 x2v = *(const float4*)&s2[cg * 4];
            float4 x3v = *(const float4*)&s3[cg * 4];
            float w0 = WkT[(256 + cg * 4 + 0) * D + d];
            float w1 = WkT[(256 + cg * 4 + 1) * D + d];
            float w2 = WkT[(256 + cg * 4 + 2) * D + d];
            float w3 = WkT[(256 + cg * 4 + 3) * D + d];
            const float* x0f = (const float*)&x0v;
            const float* x1f = (const float*)&x1v;
            const float* x2f = (const float*)&x2v;
            const float* x3f = (const float*)&x3v;
            float wj[4] = {w0, w1, w2, w3};
            #pragma unroll
            for (int j = 0; j < 4; ++j) {
                e0 = __builtin_fmaf(x0f[j], wj[j], e0);
                e1 = __builtin_fmaf(x1f[j], wj[j], e1);
                e2 = __builtin_fmaf(x2f[j], wj[j], e2);
                e3 = __builtin_fmaf(x3f[j], wj[j], e3);
            }
        }
    }

    float bkd = bk[d];
    #pragma unroll
    for (int u = 0; u < 4; ++u) {
        int pxx = pg * 4 + u;
        int dy = pxx >> 2, dx = pxx & 3;
        size_t p = (size_t)(y0 + dy) * W + (x0 + dx);
        float a = (u == 0 ? a0 : u == 1 ? a1 : u == 2 ? a2 : a3);
        float e = (u == 0 ? e0 : u == 1 ? e1 : u == 2 ? e2 : e3);
        k32[((size_t)b * HW + p) * D + d] = (a + e) + bkd;
    }
}

// ---------------------------------------------------------------- K1b: q from emb (frozen chain, R11)
__global__ __launch_bounds__(256) void k_q(
    const float* __restrict__ emb, const float* __restrict__ WqT,
    const float* __restrict__ bq, float* __restrict__ q32) {
    int t  = threadIdx.x;
    int d  = t & 63;
    int ng = t >> 6;
    int r0 = blockIdx.x * 16 + ng * 4;
    const float* e0 = emb + (size_t)(r0 + 0) * C;
    const float* e1 = emb + (size_t)(r0 + 1) * C;
    const float* e2 = emb + (size_t)(r0 + 2) * C;
    const float* e3 = emb + (size_t)(r0 + 3) * C;

    float qa0 = 0.f, qa1 = 0.f, qa2 = 0.f, qa3 = 0.f;
    float qe0 = 0.f, qe1 = 0.f, qe2 = 0.f, qe3 = 0.f;
    #pragma unroll 2
    for (int cg = 0; cg < 96; ++cg) {
        float4 v0 = *(const float4*)&e0[cg * 4];
        float4 v1 = *(const float4*)&e1[cg * 4];
        float4 v2 = *(const float4*)&e2[cg * 4];
        float4 v3 = *(const float4*)&e3[cg * 4];
        float w0 = WqT[(cg * 4 + 0) * D + d];
        float w1 = WqT[(cg * 4 + 1) * D + d];
        float w2 = WqT[(cg * 4 + 2) * D + d];
        float w3 = WqT[(cg * 4 + 3) * D + d];
        const float* f0 = (const float*)&v0;
        const float* f1 = (const float*)&v1;
        const float* f2 = (const float*)&v2;
        const float* f3 = (const float*)&v3;
        float wj[4] = {w0, w1, w2, w3};
        #pragma unroll
        for (int j = 0; j < 4; ++j) {
            qa0 = __builtin_fmaf(f0[j], wj[j], qa0);
            qa1 = __builtin_fmaf(f1[j], wj[j], qa1);
            qa2 = __builtin_fmaf(f2[j], wj[j], qa2);
            qa3 = __builtin_fmaf(f3[j], wj[j], qa3);
        }
    }
    #pragma unroll 2
    for (int cg = 96; cg < 128; ++cg) {
        float4 v0 = *(const float4*)&e0[cg * 4];
        float4 v1 = *(const float4*)&e1[cg * 4];
        float4 v2 = *(const float4*)&e2[cg * 4];
        float4 v3 = *(const float4*)&e3[cg * 4];
        float w0 = WqT[(cg * 4 + 0) * D + d];
        float w1 = WqT[(cg * 4 + 1) * D + d];
        float w2 = WqT[(cg * 4 + 2) * D + d];
        float w3 = WqT[(cg * 4 + 3) * D + d];
        const float* f0 = (const float*)&v0;
        const float* f1 = (const float*)&v1;
        const float* f2 = (const float*)&v2;
        const float* f3 = (const float*)&v3;
        float wj[4] = {w0, w1, w2, w3};
        #pragma unroll
        for (int j = 0; j < 4; ++j) {
            qe0 = __builtin_fmaf(f0[j], wj[j], qe0);
            qe1 = __builtin_fmaf(f1[j], wj[j], qe1);
            qe2 = __builtin_fmaf(f2[j], wj[j], qe2);
            qe3 = __builtin_fmaf(f3[j], wj[j], qe3);
        }
    }
    float bqd = bq[d];
    q32[(size_t)(r0 + 0) * D + d] = (qa0 + qe0) + bqd;
    q32[(size_t)(r0 + 1) * D + d] = (qa1 + qe1) + bqd;
    q32[(size_t)(r0 + 2) * D + d] = (qa2 + qe2) + bqd;
    q32[(size_t)(r0 + 3) * D + d] = (qa3 + qe3) + bqd;
}

// ---------------------------------------------------------------- K2: scores SHADOW via bf16 MFMA (R13)
__global__ __launch_bounds__(256, 4) void k_scores(
    const float* __restrict__ q32, const float* __restrict__ k32,
    _Float16* __restrict__ S16) {
    __shared__ unsigned short sQ[64 * 72];       // [row n][d], pad 72
    __shared__ unsigned short sK[64 * 72];       // [row p][d]
    __shared__ unsigned short sOut[4][16 * 72];  // per-wave repack

    int t  = threadIdx.x;
    int p0 = blockIdx.x * 64;      // 144
    int n0 = blockIdx.y * 64;      // 9
    int b  = blockIdx.z;

    const float* qb = q32 + ((size_t)b * NB + n0) * D;
    const float* kb = k32 + ((size_t)b * HW + p0) * D;

    #pragma unroll
    for (int r = 0; r < 4; ++r) {
        int L = r * 256 + t;
        int row = L >> 4, c4 = L & 15;
        float4 vq = *(const float4*)&qb[(size_t)row * D + c4 * 4];
        float4 vk = *(const float4*)&kb[(size_t)row * D + c4 * 4];
        ushort4 hq, hk;
        hq.x = f2bf(vq.x); hq.y = f2bf(vq.y); hq.z = f2bf(vq.z); hq.w = f2bf(vq.w);
        hk.x = f2bf(vk.x); hk.y = f2bf(vk.y); hk.z = f2bf(vk.z); hk.w = f2bf(vk.w);
        *(ushort4*)&sQ[row * 72 + c4 * 4] = hq;
        *(ushort4*)&sK[row * 72 + c4 * 4] = hk;
    }
    __syncthreads();

    int w = t >> 6, l = t & 63;
    int fr = l & 15;
    int kb8 = (l >> 4) * 8;

    f32x4 acc[4] = {f32x4{0,0,0,0}, f32x4{0,0,0,0}, f32x4{0,0,0,0}, f32x4{0,0,0,0}};
    #pragma unroll
    for (int ks = 0; ks < 2; ++ks) {
        bf16x8 a = *(const bf16x8*)&sQ[(16 * w + fr) * 72 + ks * 32 + kb8];
        #pragma unroll
        for (int f = 0; f < 4; ++f) {
            bf16x8 bb = *(const bf16x8*)&sK[(16 * f + fr) * 72 + ks * 32 + kb8];
            acc[f] = __builtin_amdgcn_mfma_f32_16x16x32_bf16(a, bb, acc[f], 0, 0, 0);
        }
    }

    unsigned short* so = &sOut[w][0];
    #pragma unroll
    for (int f = 0; f < 4; ++f)
        #pragma unroll
        for (int r = 0; r < 4; ++r) {
            _Float16 h = (_Float16)acc[f][r];
            so[((l >> 4) * 4 + r) * 72 + 16 * f + (l & 15)] = *(unsigned short*)&h;
        }
    __syncthreads();

    _Float16* Sb = S16 + (size_t)b * NB * HW;
    int orow = l >> 2, oc = (l & 3) * 16;
    uint4 v0 = *(const uint4*)&sOut[w][orow * 72 + oc];
    uint4 v1 = *(const uint4*)&sOut[w][orow * 72 + oc + 8];
    size_t base = (size_t)(n0 + 16 * w + orow) * HW + (p0 + oc);
    *(uint4*)&Sb[base]     = v0;
    *(uint4*)&Sb[base + 8] = v1;
}

// ---------------------------------------------------------------- K3: per-row top-k via 2-pass radix select
// v2: wave-shuffle suffix scans (3 barriers/pass) + 8-way bank-parallel histograms
__global__ __launch_bounds__(256) void k_topk(
    const _Float16* __restrict__ S16,
    const float* __restrict__ q32, const float* __restrict__ k32,
    int* __restrict__ cidx, float* __restrict__ cval, double* __restrict__ rowss) {
    __shared__ int    hist2[256][9];   // [bin][copy 0..7 + pad] -> hot bins hit 8 banks
    __shared__ int    sfx[256];
    __shared__ int    wtot[4];
    __shared__ int    b0s, mAbove, thrS, gcnt;
    __shared__ int    cps[CAP];
    __shared__ float  cv[CAP];
    __shared__ int    cp[CAP];
    __shared__ float  sv[CAP];
    __shared__ int    sp[CAP];
    __shared__ double ssq[TOPK];

    int t   = threadIdx.x;
    int row = blockIdx.x;            // b*NB + n
    int b = row / NB, n = row % NB;
    int l = t & 63, w = t >> 6;
    int cpy = t & 7;

    #pragma unroll
    for (int i = 0; i < 9; ++i) hist2[t][i] = 0;
    if (t == 0) gcnt = 0;
    __syncthreads();

    // load 36 fp16/thread, mono-transform, mask (once per quad), histogram high byte
    const unsigned short* Srow = (const unsigned short*)(S16 + (size_t)row * HW);
    unsigned int my[36];
    #pragma unroll
    for (int c = 0; c < 9; ++c) {
        ushort4 v4 = ((const ushort4*)Srow)[c * 256 + t];
        int base = (c * 256 + t) * 4;            // 4-aligned; W%4==0 -> quad shares bid
        int hh = base / W, ww = base - hh * W;
        bool selfb = (((hh >> 2) * NBH + (ww >> 2)) == n);
        #pragma unroll
        for (int j = 0; j < 4; ++j) {
            unsigned int h = (j == 0 ? v4.x : j == 1 ? v4.y : j == 2 ? v4.z : v4.w);
            unsigned int m = (h & 0x8000u) ? (h ^ 0xFFFFu) : (h | 0x8000u);
            if (selfb) m = 0;
            my[c * 4 + j] = m;
            atomicAdd(&hist2[m >> 8][cpy], 1);
        }
    }
    __syncthreads();

    // pass 1 suffix scan: wave shuffle + cross-wave totals
    {
        int v = 0;
        #pragma unroll
        for (int i = 0; i < 8; ++i) v += hist2[t][i];
        #pragma unroll
        for (int off = 1; off < 64; off <<= 1) {
            int u = __shfl_down(v, off, 64);
            if (l + off < 64) v += u;
        }
        if (l == 0) wtot[w] = v;
        __syncthreads();
        int add = 0;
        #pragma unroll
        for (int w2 = 0; w2 < 4; ++w2) if (w2 > w) add += wtot[w2];
        sfx[t] = v + add;
    }
    __syncthreads();
    if (sfx[t] >= NCAND && (t == 255 || sfx[t + 1] < NCAND)) {
        b0s = t; mAbove = (t == 255) ? 0 : sfx[t + 1];
    }
    __syncthreads();
    int b0 = b0s, mab = mAbove;

    // pass 2: low byte among high byte == b0
    #pragma unroll
    for (int i = 0; i < 9; ++i) hist2[t][i] = 0;
    __syncthreads();
    #pragma unroll
    for (int i = 0; i < 36; ++i)
        if ((int)(my[i] >> 8) == b0) atomicAdd(&hist2[my[i] & 255u][cpy], 1);
    __syncthreads();
    {
        int v = 0;
        #pragma unroll
        for (int i = 0; i < 8; ++i) v += hist2[t][i];
        #pragma unroll
        for (int off = 1; off < 64; off <<= 1) {
            int u = __shfl_down(v, off, 64);
            if (l + off < 64) v += u;
        }
        if (l == 0) wtot[w] = v;
        __syncthreads();
        int add = 0;
        #pragma unroll
        for (int w2 = 0; w2 < 4; ++w2) if (w2 > w) add += wtot[w2];
        sfx[t] = v + add;
    }
    __syncthreads();
    if (mab + sfx[t] >= NCAND && (t == 255 || mab + sfx[t + 1] < NCAND))
        thrS = (b0 << 8) | t;
    __syncthreads();
    unsigned int thr = (unsigned int)thrS;

    // gather all candidates with mono >= thr (ties incl, cap CAP)
    #pragma unroll
    for (int i = 0; i < 36; ++i) {
        if (my[i] >= thr) {
            int pos = atomicAdd(&gcnt, 1);
            if (pos < CAP) {
                int c = i >> 2, j = i & 3;
                cps[pos] = (c * 256 + t) * 4 + j;
            }
        }
    }
    __syncthreads();
    int M = min(gcnt, CAP);

    // exact fp32 re-rank — np.einsum SSE order, no FMA (NUMERICS FROZEN)
    if (t < M) {
        #pragma clang fp contract(off)
        int p = cps[t];
        const float* qr = q32 + (size_t)row * D;
        const float* kr = k32 + ((size_t)b * HW + p) * D;
        float L0 = 0.f, L1 = 0.f, L2 = 0.f, L3 = 0.f;
        #pragma unroll
        for (int j = 0; j < 16; ++j) {
            L0 = L0 + qr[4 * j + 0] * kr[4 * j + 0];
            L1 = L1 + qr[4 * j + 1] * kr[4 * j + 1];
            L2 = L2 + qr[4 * j + 2] * kr[4 * j + 2];
            L3 = L3 + qr[4 * j + 3] * kr[4 * j + 3];
        }
        cv[t] = (L0 + L1) + (L2 + L3);
        cp[t] = p;
    }
    __syncthreads();

    if (t < M) {
        float v = cv[t]; int p = cp[t];
        int rank = 0;
        for (int j = 0; j < M; ++j) {
            float vj = cv[j];
            rank += (vj > v) || (vj == v && cp[j] < p);
        }
        sv[rank] = v; sp[rank] = p;
    }
    __syncthreads();

    if (t < TK2) {
        cval[(size_t)row * TK2 + t] = sv[t];
        cidx[(size_t)row * TK2 + t] = sp[t];
    }
    if (t < TOPK) {
        double vi = (double)sv[t], s = 0.0;
        #pragma unroll
        for (int j = 0; j < TK2; ++j) { double dd = vi - (double)sv[j]; s += dd * dd; }
        ssq[t] = s;
    }
    __syncthreads();
    if (t == 0) {
        double s = 0.0;
        #pragma unroll
        for (int i = 0; i < TOPK; ++i) s += ssq[i];
        rowss[row] = s;
    }
}

// ---------------------------------------------------------------- K4: per-batch RMS -> scale
__global__ void k_rms(const double* __restrict__ rowss, double* __restrict__ scale) {
    __shared__ double sb[256];
    int b = blockIdx.x, t = threadIdx.x;
    double s = 0.0;
    for (int r = t; r < NB; r += 256) s += rowss[b * NB + r];
    sb[t] = s; __syncthreads();
    for (int st = 128; st > 0; st >>= 1) {
        if (t < st) sb[t] += sb[t + st];
        __syncthreads();
    }
    if (t == 0) {
        double rms = sqrt(sb[0] / ((double)NB * TOPK * TK2));
        scale[b] = 10.0 / (rms + 1e-3);
    }
}

// ---------------------------------------------------------------- K5: finalize — SOLE writer of d_out (float32)
__global__ __launch_bounds__(256) void k_final(
    const int* __restrict__ cidx, const float* __restrict__ cval,
    const double* __restrict__ scale, float* __restrict__ out) {
    __shared__ double sv[16][TK2];
    int t = threadIdx.x;
    int row0 = blockIdx.x * 16;
    for (int idx = t; idx < 16 * TK2; idx += 256) {
        int r = idx >> 5, j = idx & 31;
        sv[r][j] = (double)cval[(size_t)(row0 + r) * TK2 + j];
    }
    __syncthreads();
    int r = t >> 4, i = t & 15;
    int row = row0 + r;
    double scb = scale[row / NB];
    double vi = sv[r][i];
    double s = 0.0;
    #pragma unroll
    for (int j = 0; j < TK2; ++j) {
        double x = (vi - sv[r][j]) * scb;
        s += 1.0 / (1.0 + exp(-x));
    }
    out[(size_t)B * NB * TOPK + (size_t)row * TOPK + i] = (float)tanh(s - (double)TOPK);
    out[(size_t)row * TOPK + i] = (float)cidx[(size_t)row * TK2 + i];
}

// ---------------------------------------------------------------- sentinel fill (ws too small)
__global__ void k_fill(float* out, int nelem) {
    int i = blockIdx.x * 256 + threadIdx.x;
    if (i < nelem) out[i] = -12345.0f;
}

// ---------------------------------------------------------------- launch
extern "C" void kernel_launch(void* const* d_in, const int* in_sizes, int n_in,
                              void* d_out, int out_size, void* d_ws, size_t ws_size,
                              hipStream_t stream) {
    const float* src = (const float*)d_in[0];
    const float* Wq  = (const float*)d_in[1];
    const float* bq  = (const float*)d_in[2];
    const float* Wk  = (const float*)d_in[3];
    const float* bk  = (const float*)d_in[4];
    float* out = (float*)d_out;

    char* ws = (char*)d_ws;
    size_t oWkT = 0;
    size_t oWqT = oWkT + (size_t)C * D * 4;
    size_t oQ   = oWqT + (size_t)C * D * 4;
    size_t oK   = oQ   + (size_t)B * NB * D * 4;
    size_t oS   = oK   + (size_t)B * HW * D * 4;
    size_t oEmb = oS   + (size_t)B * NB * HW * 2;
    size_t oCV  = oEmb + (size_t)B * NB * C * 4;
    size_t oCI  = oCV  + (size_t)B * NB * TK2 * 4;
    size_t oRS  = oCI  + (size_t)B * NB * TK2 * 4;
    size_t oSc  = oRS  + (size_t)B * NB * 8;
    size_t need = oSc  + (size_t)B * 8;

    if (ws_size < need) {
        k_fill<<<(out_size + 255) / 256, 256, 0, stream>>>(out, out_size);
        return;
    }

    float*     WkT  = (float*)(ws + oWkT);
    float*     WqT  = (float*)(ws + oWqT);
    float*     q32  = (float*)(ws + oQ);
    float*     k32  = (float*)(ws + oK);
    _Float16*  S16  = (_Float16*)(ws + oS);
    float*     emb  = (float*)(ws + oEmb);
    float*     cval = (float*)(ws + oCV);
    int*       cidx = (int*)(ws + oCI);
    double*    rss  = (double*)(ws + oRS);
    double*    scl  = (double*)(ws + oSc);

    k_transpose<<<(C * D + 255) / 256, 256, 0, stream>>>(Wk, Wq, WkT, WqT);
    k_embed<<<B * NB, 256, 0, stream>>>(src, WkT, bk, k32, emb);
    k_q<<<B * NB / 16, 256, 0, stream>>>(emb, WqT, bq, q32);
    k_scores<<<dim3(HW / 64, NB / 64, B), 256, 0, stream>>>(q32, k32, S16);
    k_topk<<<B * NB, 256, 0, stream>>>(S16, q32, k32, cidx, cval, rss);
    k_rms<<<B, 256, 0, stream>>>(rss, scl);
    k_final<<<B * NB / 16, 256, 0, stream>>>(cidx, cval, scl, out);
}